// Round 1
// 461.494 us; speedup vs baseline: 1.0058x; 1.0058x over previous
//
#include <hip/hip_runtime.h>

// PartialProductAccumulator: 54-step ripple add with dropped carry-out
// == sum of 54 partial products mod 2^108.
// FUSED single kernel, v2 (within-plane-contiguous in-flight window):
//   phase 1: per-bit-column popcount (exact in fp32, max 54). Each thread
//            owns TWO float4 chunks per plane (block window = 864 f4 =
//            13.8 KB contiguous per plane). Pipeline is only ONE plane
//            deep: in-flight loads span <=3 planes (vs 8 in v1) and are
//            mostly contiguous within one plane window. Rationale: plane
//            stride = 27*2^18 B, so cross-plane in-flight requests share
//            address bits [0:17] and alias onto the same HBM channel/bank
//            set -> row thrash (v1 streamed at ~1.7 TB/s vs 6.5 TB/s
//            memset on the same buffer). nt loads kept (R5 A/B: removing
//            nt cost +29us).
//   phase 2: counts -> LDS (stride 109, conflict-free: 109 mod 32 = 13,
//            odd), threads 0..31 do the serial 108-step carry
//            (t = cnt + c; bit = t&1; c = t>>1), then all 432 threads
//            write the output tile contiguously with nt stores.
// Block = 432 threads; each block covers 32 batch rows (864 f4 per plane);
// grid = 512 blocks = 2 blocks/CU = 13.5 waves/CU.

#define N_PP   54
#define BITS   108
#define BATCH  16384
#define ROW_F4 (BITS / 4)                    // 27 float4 per row
#define PLANE_F4 ((size_t)BATCH * ROW_F4)    // 442368 float4 per p-plane
#define TPB     432                          // threads per block
#define CPT     2                            // float4 chunks per thread per plane
#define BLK_F4  (TPB * CPT)                  // 864 f4 per block per plane
#define ROWS_PB (BLK_F4 / ROW_F4)            // 32 batch rows per block
#define GRID    ((int)(PLANE_F4 / BLK_F4))   // 512 blocks

typedef float vf4 __attribute__((ext_vector_type(4)));

__global__ __launch_bounds__(TPB)
void ppacc_fused(const vf4* __restrict__ pps, vf4* __restrict__ out) {
    __shared__ float counts[ROWS_PB][BITS + 1];   // stride 109 = 13 mod 32

    const int tid = threadIdx.x;
    const size_t base = (size_t)blockIdx.x * BLK_F4 + tid;
    const vf4* p = pps + base;                    // chunk0; chunk1 at +TPB

    // ---- phase 1: column popcount, 1-plane-deep pipeline ----
    vf4 acc0 = (vf4)(0.f), acc1 = (vf4)(0.f);

    // a = plane q, b = plane q+1
    vf4 a0 = __builtin_nontemporal_load(p);
    vf4 a1 = __builtin_nontemporal_load(p + TPB);
    vf4 b0 = __builtin_nontemporal_load(p + PLANE_F4);
    vf4 b1 = __builtin_nontemporal_load(p + PLANE_F4 + TPB);

    const vf4* pn = p + 2 * PLANE_F4;             // plane q+2 cursor
#pragma unroll 4
    for (int q = 0; q < N_PP - 2; ++q) {          // consume planes 0..51
        vf4 c0 = __builtin_nontemporal_load(pn);
        vf4 c1 = __builtin_nontemporal_load(pn + TPB);
        pn += PLANE_F4;
        acc0 += a0; acc1 += a1;
        a0 = b0; a1 = b1;
        b0 = c0; b1 = c1;
    }
    acc0 += a0; acc1 += a1;                       // plane 52
    acc0 += b0; acc1 += b1;                       // plane 53

    // ---- phase 2: carry propagation through LDS ----
    const int rr = tid / ROW_F4;                  // 0..15 (chunk0 row)
    const int bb = (tid % ROW_F4) * 4;            // bit column base
    counts[rr][bb + 0] = acc0.x;
    counts[rr][bb + 1] = acc0.y;
    counts[rr][bb + 2] = acc0.z;
    counts[rr][bb + 3] = acc0.w;
    counts[rr + 16][bb + 0] = acc1.x;             // chunk1 row = rr + 16
    counts[rr + 16][bb + 1] = acc1.y;
    counts[rr + 16][bb + 2] = acc1.z;
    counts[rr + 16][bb + 3] = acc1.w;
    __syncthreads();

    if (tid < ROWS_PB) {
        int c = 0;
#pragma unroll
        for (int i = 0; i < BITS; ++i) {
            const int t = (int)counts[tid][i] + c;
            counts[tid][i] = (float)(t & 1);
            c = t >> 1;                           // carry out of bit 107 dropped
        }
    }
    __syncthreads();

    {
        vf4 v0, v1;
        v0.x = counts[rr][bb + 0];
        v0.y = counts[rr][bb + 1];
        v0.z = counts[rr][bb + 2];
        v0.w = counts[rr][bb + 3];
        v1.x = counts[rr + 16][bb + 0];
        v1.y = counts[rr + 16][bb + 1];
        v1.z = counts[rr + 16][bb + 2];
        v1.w = counts[rr + 16][bb + 3];
        __builtin_nontemporal_store(v0, out + base);
        __builtin_nontemporal_store(v1, out + base + TPB);
    }
}

extern "C" void kernel_launch(void* const* d_in, const int* in_sizes, int n_in,
                              void* d_out, int out_size, void* d_ws, size_t ws_size,
                              hipStream_t stream) {
    const vf4* pps = (const vf4*)d_in[0];
    vf4* out = (vf4*)d_out;
    ppacc_fused<<<GRID, TPB, 0, stream>>>(pps, out);
}